// Round 1
// baseline (3044.355 us; speedup 1.0000x reference)
//
#include <hip/hip_runtime.h>

// TriPlaneField: 4-scale triplane bilinear sampling with cumulative-sum feature concat.
// pts: [N,3] fp32; grids_s{0..3}: [3, 72, r, r] fp32, r in {64,128,256,512}.
// out: [N, 4*3*72] fp32, laid out scale-major then plane then channel;
//      scale s block holds cumulative sum of samples for scales 0..s.

#define TP_C 72
#define TP_PLANES 3
#define TP_SCALES 4
#define TP_INV_BOUNDS 0.625f  // 1/1.6

__global__ __launch_bounds__(256) void triplane_kernel(
    const float* __restrict__ pts,
    const float* __restrict__ g0,
    const float* __restrict__ g1,
    const float* __restrict__ g2,
    const float* __restrict__ g3,
    float* __restrict__ out,
    int N)
{
    int idx = blockIdx.x * blockDim.x + threadIdx.x;
    int total = N * TP_PLANES * TP_C;
    if (idx >= total) return;

    int c = idx % TP_C;
    int t = idx / TP_C;
    int p = t % TP_PLANES;
    int n = t / TP_PLANES;

    // normalize_aabb with aabb [[1.6]*3, [-1.6]*3] reduces to pts_n = -pts/1.6
    float nx = -pts[n * 3 + 0] * TP_INV_BOUNDS;
    float ny = -pts[n * 3 + 1] * TP_INV_BOUNDS;
    float nz = -pts[n * 3 + 2] * TP_INV_BOUNDS;

    // plane coordinate combos: p0 -> (d0,d1), p1 -> (d0,d2), p2 -> (d1,d2)
    float cx, cy;
    if (p == 0)      { cx = nx; cy = ny; }
    else if (p == 1) { cx = nx; cy = nz; }
    else             { cx = ny; cy = nz; }

    const float* grids[TP_SCALES] = { g0, g1, g2, g3 };
    const int    res[TP_SCALES]   = { 64, 128, 256, 512 };

    float acc = 0.0f;
    float* outrow = out + (size_t)n * (TP_SCALES * TP_PLANES * TP_C);

    #pragma unroll
    for (int s = 0; s < TP_SCALES; ++s) {
        const int r = res[s];
        const float rm1 = (float)(r - 1);

        // align_corners=True mapping, then border clamp of the pixel coord
        float fx = (cx + 1.0f) * 0.5f * rm1;
        float fy = (cy + 1.0f) * 0.5f * rm1;
        fx = fminf(fmaxf(fx, 0.0f), rm1);
        fy = fminf(fmaxf(fy, 0.0f), rm1);

        float x0f = floorf(fx);
        float y0f = floorf(fy);
        float wx = fx - x0f;
        float wy = fy - y0f;
        int x0 = (int)x0f;
        int y0 = (int)y0f;
        int x1 = min(x0 + 1, r - 1);
        int y1 = min(y0 + 1, r - 1);

        // grid scale s, plane p, channel c: base of an r*r image
        const float* g = grids[s] + ((size_t)p * TP_C + c) * (size_t)r * (size_t)r;

        float v00 = g[y0 * r + x0];
        float v01 = g[y0 * r + x1];
        float v10 = g[y1 * r + x0];
        float v11 = g[y1 * r + x1];

        // match reference formula ordering
        float top = v00 * (1.0f - wx) + v01 * wx;
        float bot = v10 * (1.0f - wx) + v11 * wx;
        float val = top * (1.0f - wy) + bot * wy;

        acc += val;
        outrow[s * (TP_PLANES * TP_C) + p * TP_C + c] = acc;
    }
}

extern "C" void kernel_launch(void* const* d_in, const int* in_sizes, int n_in,
                              void* d_out, int out_size, void* d_ws, size_t ws_size,
                              hipStream_t stream) {
    const float* pts = (const float*)d_in[0];
    const float* g0  = (const float*)d_in[1];
    const float* g1  = (const float*)d_in[2];
    const float* g2  = (const float*)d_in[3];
    const float* g3  = (const float*)d_in[4];
    float* out = (float*)d_out;

    int N = in_sizes[0] / 3;
    int total = N * TP_PLANES * TP_C;
    int block = 256;
    int grid = (total + block - 1) / block;

    triplane_kernel<<<grid, block, 0, stream>>>(pts, g0, g1, g2, g3, out, N);
}

// Round 2
// 822.987 us; speedup vs baseline: 3.6992x; 3.6992x over previous
//
#include <hip/hip_runtime.h>

// TriPlaneField: 4-scale triplane bilinear sampling with cumulative-sum concat.
// Strategy: (1) transpose grids [3,C,r,r] -> [3,r,r,C] into d_ws (LDS-tiled,
// coalesced both sides) so channel gathers are contiguous; (2) gather kernel
// with one thread per (point, plane, 4-channel group) using float4 loads.

#define TP_C 72
#define TP_PLANES 3
#define TP_SCALES 4
#define TP_INV_BOUNDS 0.625f  // 1/1.6
#define TP_CVEC (TP_C / 4)    // 18 float4 groups per (n,p)

// ---------------- transpose: [3, C, r, r] -> [3, r, r, C] ----------------
// For each (plane p, row y): transpose the (C x r) matrix M[c][x] into T[x][c].
// Block (32,8); grid (r/32, ceil(C/32)=3, 3*r).
__global__ __launch_bounds__(256) void transpose_kernel(
    const float* __restrict__ in, float* __restrict__ out, int r)
{
    __shared__ float tile[32][33];

    int xt = blockIdx.x * 32;
    int ct = blockIdx.y * 32;
    int py = blockIdx.z;          // p * r + y
    int p  = py / r;
    int y  = py - p * r;
    int tx = threadIdx.x;
    int ty = threadIdx.y;

    const float* inp = in + ((size_t)p * TP_C) * (size_t)r * (size_t)r + (size_t)y * r;

    #pragma unroll
    for (int i = 0; i < 4; ++i) {
        int c = ct + ty + i * 8;
        if (c < TP_C) {
            tile[ty + i * 8][tx] = inp[(size_t)c * r * r + xt + tx];
        }
    }
    __syncthreads();

    float* outp = out + ((size_t)py * r) * TP_C;  // ((p*r + y) * r) * C
    #pragma unroll
    for (int i = 0; i < 4; ++i) {
        int x = xt + ty + i * 8;
        int c = ct + tx;
        if (c < TP_C) {
            outp[(size_t)x * TP_C + c] = tile[tx][ty + i * 8];
        }
    }
}

// ---------------- gather: bilinear sample from channel-last grids ----------------
__global__ __launch_bounds__(256) void triplane_gather_kernel(
    const float* __restrict__ pts,
    const float* __restrict__ t0,
    const float* __restrict__ t1,
    const float* __restrict__ t2,
    const float* __restrict__ t3,
    float* __restrict__ out,
    int N)
{
    int idx = blockIdx.x * blockDim.x + threadIdx.x;
    int total = N * TP_PLANES * TP_CVEC;
    if (idx >= total) return;

    int cv = idx % TP_CVEC;           // which float4 group of channels
    int t  = idx / TP_CVEC;
    int p  = t % TP_PLANES;
    int n  = t / TP_PLANES;

    float nx = -pts[n * 3 + 0] * TP_INV_BOUNDS;
    float ny = -pts[n * 3 + 1] * TP_INV_BOUNDS;
    float nz = -pts[n * 3 + 2] * TP_INV_BOUNDS;

    float cx, cy;
    if (p == 0)      { cx = nx; cy = ny; }
    else if (p == 1) { cx = nx; cy = nz; }
    else             { cx = ny; cy = nz; }

    const float* grids[TP_SCALES] = { t0, t1, t2, t3 };
    const int    res[TP_SCALES]   = { 64, 128, 256, 512 };

    float4 acc = make_float4(0.f, 0.f, 0.f, 0.f);
    float* outrow = out + (size_t)n * (TP_SCALES * TP_PLANES * TP_C)
                        + (size_t)p * TP_C + cv * 4;

    #pragma unroll
    for (int s = 0; s < TP_SCALES; ++s) {
        const int r = res[s];
        const float rm1 = (float)(r - 1);

        float fx = (cx + 1.0f) * 0.5f * rm1;
        float fy = (cy + 1.0f) * 0.5f * rm1;
        fx = fminf(fmaxf(fx, 0.0f), rm1);
        fy = fminf(fmaxf(fy, 0.0f), rm1);

        float x0f = floorf(fx);
        float y0f = floorf(fy);
        float wx = fx - x0f;
        float wy = fy - y0f;
        int x0 = (int)x0f;
        int y0 = (int)y0f;
        int x1 = min(x0 + 1, r - 1);
        int y1 = min(y0 + 1, r - 1);

        // channel-last: ((p*r + y)*r + x)*C + c
        const float* g = grids[s] + ((size_t)p * r * r) * TP_C + (size_t)cv * 4;
        const float4* r0c0 = (const float4*)(g + ((size_t)y0 * r + x0) * TP_C);
        const float4* r0c1 = (const float4*)(g + ((size_t)y0 * r + x1) * TP_C);
        const float4* r1c0 = (const float4*)(g + ((size_t)y1 * r + x0) * TP_C);
        const float4* r1c1 = (const float4*)(g + ((size_t)y1 * r + x1) * TP_C);

        float4 v00 = *r0c0;
        float4 v01 = *r0c1;
        float4 v10 = *r1c0;
        float4 v11 = *r1c1;

        float iwx = 1.0f - wx;
        float iwy = 1.0f - wy;

        float tpx, tpy, tpz, tpw, bt;
        tpx = v00.x * iwx + v01.x * wx;
        bt  = v10.x * iwx + v11.x * wx;
        acc.x += tpx * iwy + bt * wy;
        tpy = v00.y * iwx + v01.y * wx;
        bt  = v10.y * iwx + v11.y * wx;
        acc.y += tpy * iwy + bt * wy;
        tpz = v00.z * iwx + v01.z * wx;
        bt  = v10.z * iwx + v11.z * wx;
        acc.z += tpz * iwy + bt * wy;
        tpw = v00.w * iwx + v01.w * wx;
        bt  = v10.w * iwx + v11.w * wx;
        acc.w += tpw * iwy + bt * wy;

        *(float4*)(outrow + s * (TP_PLANES * TP_C)) = acc;
    }
}

extern "C" void kernel_launch(void* const* d_in, const int* in_sizes, int n_in,
                              void* d_out, int out_size, void* d_ws, size_t ws_size,
                              hipStream_t stream) {
    const float* pts = (const float*)d_in[0];
    const float* g[TP_SCALES] = {
        (const float*)d_in[1], (const float*)d_in[2],
        (const float*)d_in[3], (const float*)d_in[4] };
    float* out = (float*)d_out;

    const int res[TP_SCALES] = { 64, 128, 256, 512 };

    // ws layout: transposed grids, scale-major
    float* tg[TP_SCALES];
    size_t off = 0;
    for (int s = 0; s < TP_SCALES; ++s) {
        tg[s] = (float*)d_ws + off;
        off += (size_t)TP_PLANES * TP_C * res[s] * res[s];
    }

    for (int s = 0; s < TP_SCALES; ++s) {
        int r = res[s];
        dim3 block(32, 8);
        dim3 grid(r / 32, (TP_C + 31) / 32, TP_PLANES * r);
        transpose_kernel<<<grid, block, 0, stream>>>(g[s], tg[s], r);
    }

    int N = in_sizes[0] / 3;
    int total = N * TP_PLANES * TP_CVEC;
    int block = 256;
    int grid = (total + block - 1) / block;
    triplane_gather_kernel<<<grid, block, 0, stream>>>(
        pts, tg[0], tg[1], tg[2], tg[3], out, N);
}